// Round 8
// baseline (67.182 us; speedup 1.0000x reference)
//
#include <hip/hip_runtime.h>

#define N_POINTS 204800
#define N_GT 256
#define BLOCK 512            // 8 waves
#define PTS_PER_BLOCK 512    // 64 lanes x 8 points/thread
#define GRID (N_POINTS / PTS_PER_BLOCK)  // 400 blocks

typedef float v2f __attribute__((ext_vector_type(2)));

// Packed fp32 FMA as native vector IR -> llvm.fma.v2f32 -> v_pk_fma_f32.
__device__ __forceinline__ v2f pk_fma(v2f a, v2f b, v2f c) {
  return __builtin_elementwise_fma(a, b, c);
}
__device__ __forceinline__ v2f lohalf(float4 q) { return (v2f){q.x, q.y}; }
__device__ __forceinline__ v2f hihalf(float4 q) { return (v2f){q.z, q.w}; }

// Math (R1-R7): per box, centerness^2 = max(fx,0)*fy under a >=0 max-reduce
// (one-clamp), fx/fy quadratics in px/py, division folded into coefficients,
// sqrt hoisted out of the 256-box max. Coef layout 24B/box x/y-interleaved so
// every v2f operand is an even-aligned half of a ds_read_b128 result.
//
// R8: software-pipelined coefficient stream. R7's residual ~10us matched
// LDS(3.8us) + VALU(5.5us) SERIALIZED: unroll-1 made each wave alternate
// [6x ds_read -> lgkmcnt(0) -> 144 VALU] with all 16 waves in lockstep.
// Two register buffers (A/B), loads issued one 4-box group ahead of use ->
// fine-grained lgkmcnt waits, LDS pipe overlaps VALU pipe -> pay max not sum.
__global__ __launch_bounds__(BLOCK, 4) void centerness_kernel(
    const float* __restrict__ points, const float* __restrict__ gt,
    float* __restrict__ out) {
  __shared__ float scoef[6 * N_GT];   // 24B/box, x/y-interleaved (6144 B)
  __shared__ float spart[8 * 512];    // per-wave partial maxes (16384 B)

  const int t = threadIdx.x;
  const int lane = t & 63;
  const int w = t >> 6;  // wave id = 32-box chunk id

  // --- issue point loads first (independent of staging) ---
  const int base4 = blockIdx.x * 256;  // float4 index; each f4 = 2 points
  const float4* p4 = (const float4*)points;
  float4 pA = p4[base4 + lane];
  float4 pB = p4[base4 + 64 + lane];
  float4 pC = p4[base4 + 128 + lane];
  float4 pD = p4[base4 + 192 + lane];

  // --- stage coefficients: one box per thread (threads 0..255) ---
  if (t < N_GT) {
    float4 b = ((const float4*)gt)[t];  // x1,y1,x2,y2
    float iw = 1.0f / (b.z - b.x);
    float ih = 1.0f / (b.w - b.y);
    float* c = &scoef[6 * t];
    c[0] = -iw;               c[1] = -ih;
    c[2] = (b.x + b.z) * iw;  c[3] = (b.y + b.w) * ih;
    c[4] = -(b.x * b.z) * iw; c[5] = -(b.y * b.w) * ih;
  }
  __syncthreads();

  v2f P[8];
  P[0] = lohalf(pA); P[1] = hihalf(pA);
  P[2] = lohalf(pB); P[3] = hihalf(pB);
  P[4] = lohalf(pC); P[5] = hihalf(pC);
  P[6] = lohalf(pD); P[7] = hihalf(pD);

  float acc[8];
#pragma unroll
  for (int p = 0; p < 8; ++p) acc[p] = 0.0f;

  const float4* cw = (const float4*)scoef + w * 48;  // this wave's 32 boxes

  // 4-box group compute from 6 float4 regs (broadcast ds_read results).
  // box0: a2=lo(q0) a1=hi(q0) a0=lo(q1);  box1: a2=hi(q1) a1=lo(q2) a0=hi(q2)
  // box2: a2=lo(q3) a1=hi(q3) a0=lo(q4);  box3: a2=hi(q4) a1=lo(q5) a0=hi(q5)
#define COMPUTE(q0, q1, q2, q3, q4, q5)                                   \
  {                                                                       \
    v2f c0a = lohalf(q0), c0b = hihalf(q0), c0c = lohalf(q1);             \
    v2f c1a = hihalf(q1), c1b = lohalf(q2), c1c = hihalf(q2);             \
    v2f c2a = lohalf(q3), c2b = hihalf(q3), c2c = lohalf(q4);             \
    v2f c3a = hihalf(q4), c3b = lohalf(q5), c3c = hihalf(q5);             \
    _Pragma("unroll")                                                     \
    for (int p = 0; p < 8; ++p) {                                         \
      v2f Pp = P[p];                                                      \
      v2f r0 = pk_fma(pk_fma(c0a, Pp, c0b), Pp, c0c);                     \
      v2f r1 = pk_fma(pk_fma(c1a, Pp, c1b), Pp, c1c);                     \
      float v0 = fmaxf(r0.x, 0.f) * r0.y;                                 \
      float v1 = fmaxf(r1.x, 0.f) * r1.y;                                 \
      acc[p] = fmaxf(fmaxf(acc[p], v0), v1);                              \
      v2f r2 = pk_fma(pk_fma(c2a, Pp, c2b), Pp, c2c);                     \
      v2f r3 = pk_fma(pk_fma(c3a, Pp, c3b), Pp, c3c);                     \
      float v2 = fmaxf(r2.x, 0.f) * r2.y;                                 \
      float v3 = fmaxf(r3.x, 0.f) * r3.y;                                 \
      acc[p] = fmaxf(fmaxf(acc[p], v2), v3);                              \
    }                                                                     \
  }

#define LOADG(a0, a1, a2_, a3, a4, a5, idx)                               \
  a0 = cw[6 * (idx) + 0]; a1 = cw[6 * (idx) + 1]; a2_ = cw[6 * (idx) + 2];\
  a3 = cw[6 * (idx) + 3]; a4 = cw[6 * (idx) + 4]; a5 = cw[6 * (idx) + 5];

  float4 qa0, qa1, qa2, qa3, qa4, qa5;
  float4 qb0, qb1, qb2, qb3, qb4, qb5;
  LOADG(qa0, qa1, qa2, qa3, qa4, qa5, 0)
  LOADG(qb0, qb1, qb2, qb3, qb4, qb5, 1)
#pragma unroll 1
  for (int g = 0; g < 3; ++g) {
    COMPUTE(qa0, qa1, qa2, qa3, qa4, qa5)
    LOADG(qa0, qa1, qa2, qa3, qa4, qa5, 2 * g + 2)
    COMPUTE(qb0, qb1, qb2, qb3, qb4, qb5)
    LOADG(qb0, qb1, qb2, qb3, qb4, qb5, 2 * g + 3)
  }
  COMPUTE(qa0, qa1, qa2, qa3, qa4, qa5)
  COMPUTE(qb0, qb1, qb2, qb3, qb4, qb5)
#undef COMPUTE
#undef LOADG

  // --- partials to LDS: spart[w][local point id] ---
#pragma unroll
  for (int p = 0; p < 8; p += 2) {
    float2* sp2 = (float2*)&spart[w * 512 + 128 * (p >> 1)];
    sp2[lane] = make_float2(acc[p], acc[p + 1]);
  }
  __syncthreads();

  // --- all 8 waves reduce: thread t owns local point t (conflict-free) ---
  float m = spart[t];
#pragma unroll
  for (int i = 1; i < 8; ++i) m = fmaxf(m, spart[i * 512 + t]);
  out[blockIdx.x * PTS_PER_BLOCK + t] = sqrtf(m);
}

extern "C" void kernel_launch(void* const* d_in, const int* in_sizes, int n_in,
                              void* d_out, int out_size, void* d_ws, size_t ws_size,
                              hipStream_t stream) {
  const float* points = (const float*)d_in[0];     // (204800, 2)
  const float* gt_bboxes = (const float*)d_in[1];  // (256, 4)
  // d_in[2] strides: unused by the reference output.
  float* out = (float*)d_out;                      // (204800,)

  centerness_kernel<<<GRID, BLOCK, 0, stream>>>(points, gt_bboxes, out);
}

// Round 9
// 65.667 us; speedup vs baseline: 1.0231x; 1.0231x over previous
//
#include <hip/hip_runtime.h>

#define N_POINTS 204800
#define N_GT 256
#define BLOCK 1024           // 16 waves
#define GRID 256             // exactly 1 block per CU — perfect balance
#define PTS_PER_BLOCK 800    // 204800 / 256
#define NF4 (N_POINTS / 2)   // total float4 count in points array (102400)

typedef float v2f __attribute__((ext_vector_type(2)));

__device__ __forceinline__ v2f pk_fma(v2f a, v2f b, v2f c) {
  return __builtin_elementwise_fma(a, b, c);
}
__device__ __forceinline__ v2f lohalf(float4 q) { return (v2f){q.x, q.y}; }
__device__ __forceinline__ v2f hihalf(float4 q) { return (v2f){q.z, q.w}; }

// Math (R1-R8): per box, centerness^2 = max(fx,0)*fy under a >=0 max-reduce
// (one-clamp), fx/fy quadratics in px/py (div folded into coefs), sqrt
// hoisted out of the 256-box max. Coef 24B/box x/y-interleaved.
//
// R9 restructure (R5-R8 plateaued at kernel ~10us = LDS-stream + VALU + 1.28x
// grid imbalance):
//  - 256 blocks x 16 waves = exactly 1 block/CU (zero imbalance).
//  - Loop inverted: wave w owns boxes [16w,16w+16); reads each 4-box coef
//    group from LDS ONCE (24 broadcast b128/wave total, was 48) and sweeps all
//    800 block points against it. Loop LDS/CU = 384*12 = 4.6 kcyc, thin.
//  - Per-wave partials (14 regs) -> one 51.2KB LDS dump -> 16-way max reduce.
__global__ __launch_bounds__(BLOCK, 4) void centerness_kernel(
    const float* __restrict__ points, const float* __restrict__ gt,
    float* __restrict__ out) {
  __shared__ float scoef[6 * N_GT];               // 6144 B
  __shared__ float spart[16 * PTS_PER_BLOCK];     // 51200 B  (total 57344)

  const int t = threadIdx.x;
  const int lane = t & 63;
  const int w = t >> 6;  // wave id = 16-box chunk id

  // --- load this block's 800 points: 7 float4/lane (last one partial) ---
  const int pbase = blockIdx.x * 400;  // float4 index of block start
  const float4* p4 = (const float4*)points;
  float4 pt[7];
#pragma unroll
  for (int it = 0; it < 6; ++it) pt[it] = p4[pbase + it * 64 + lane];
  {
    int idx = pbase + 384 + lane;           // valid only for lane<16
    if (idx > NF4 - 1) idx = NF4 - 1;       // clamp: garbage is write-guarded
    pt[6] = p4[idx];
  }

  // --- stage coefficients (threads 0..255, one box each) ---
  if (t < N_GT) {
    float4 b = ((const float4*)gt)[t];  // x1,y1,x2,y2
    float iw = 1.0f / (b.z - b.x);
    float ih = 1.0f / (b.w - b.y);
    float* c = &scoef[6 * t];
    c[0] = -iw;               c[1] = -ih;
    c[2] = (b.x + b.z) * iw;  c[3] = (b.y + b.w) * ih;
    c[4] = -(b.x * b.z) * iw; c[5] = -(b.y * b.w) * ih;
  }
  __syncthreads();

  float acc[14];
#pragma unroll
  for (int k = 0; k < 14; ++k) acc[k] = 0.f;

  const float4* cw = (const float4*)scoef + w * 24;  // 16 boxes * 6 f / 4

#pragma unroll 1
  for (int g = 0; g < 4; ++g) {
    // 4 boxes = 6 uniform (broadcast) b128 reads, held for the point sweep.
    float4 q0 = cw[6 * g + 0];
    float4 q1 = cw[6 * g + 1];
    float4 q2 = cw[6 * g + 2];
    float4 q3 = cw[6 * g + 3];
    float4 q4 = cw[6 * g + 4];
    float4 q5 = cw[6 * g + 5];
    // box0: a2=lo(q0) a1=hi(q0) a0=lo(q1); box1: a2=hi(q1) a1=lo(q2) a0=hi(q2)
    // box2: a2=lo(q3) a1=hi(q3) a0=lo(q4); box3: a2=hi(q4) a1=lo(q5) a0=hi(q5)
    v2f c0a = lohalf(q0), c0b = hihalf(q0), c0c = lohalf(q1);
    v2f c1a = hihalf(q1), c1b = lohalf(q2), c1c = hihalf(q2);
    v2f c2a = lohalf(q3), c2b = hihalf(q3), c2c = lohalf(q4);
    v2f c3a = hihalf(q4), c3b = lohalf(q5), c3c = hihalf(q5);

#pragma unroll
    for (int it = 0; it < 7; ++it) {
      v2f P0 = lohalf(pt[it]);  // point 2*it*64+2*lane
      v2f P1 = hihalf(pt[it]);  // point ... +1
      // point 0 of the pair
      {
        v2f r0 = pk_fma(pk_fma(c0a, P0, c0b), P0, c0c);
        v2f r1 = pk_fma(pk_fma(c1a, P0, c1b), P0, c1c);
        float v0 = fmaxf(r0.x, 0.f) * r0.y;
        float v1 = fmaxf(r1.x, 0.f) * r1.y;
        acc[2 * it] = fmaxf(fmaxf(acc[2 * it], v0), v1);  // v_max3
        v2f r2 = pk_fma(pk_fma(c2a, P0, c2b), P0, c2c);
        v2f r3 = pk_fma(pk_fma(c3a, P0, c3b), P0, c3c);
        float v2 = fmaxf(r2.x, 0.f) * r2.y;
        float v3 = fmaxf(r3.x, 0.f) * r3.y;
        acc[2 * it] = fmaxf(fmaxf(acc[2 * it], v2), v3);
      }
      // point 1 of the pair
      {
        v2f r0 = pk_fma(pk_fma(c0a, P1, c0b), P1, c0c);
        v2f r1 = pk_fma(pk_fma(c1a, P1, c1b), P1, c1c);
        float v0 = fmaxf(r0.x, 0.f) * r0.y;
        float v1 = fmaxf(r1.x, 0.f) * r1.y;
        acc[2 * it + 1] = fmaxf(fmaxf(acc[2 * it + 1], v0), v1);
        v2f r2 = pk_fma(pk_fma(c2a, P1, c2b), P1, c2c);
        v2f r3 = pk_fma(pk_fma(c3a, P1, c3b), P1, c3c);
        float v2 = fmaxf(r2.x, 0.f) * r2.y;
        float v3 = fmaxf(r3.x, 0.f) * r3.y;
        acc[2 * it + 1] = fmaxf(fmaxf(acc[2 * it + 1], v2), v3);
      }
    }
  }

  // --- dump per-wave partials: spart[w][pid], pid = it*128 + 2*lane (+1) ---
#pragma unroll
  for (int it = 0; it < 6; ++it) {
    float2* row = (float2*)&spart[w * PTS_PER_BLOCK + it * 128];
    row[lane] = make_float2(acc[2 * it], acc[2 * it + 1]);
  }
  if (lane < 16) {  // it=6: only 32 valid points (768..799)
    float2* row = (float2*)&spart[w * PTS_PER_BLOCK + 768];
    row[lane] = make_float2(acc[12], acc[13]);
  }
  __syncthreads();

  // --- 16-way max reduce: thread t owns point t (t < 800) ---
  if (t < PTS_PER_BLOCK) {
    float m = spart[t];
#pragma unroll
    for (int i = 1; i < 16; ++i) m = fmaxf(m, spart[i * PTS_PER_BLOCK + t]);
    out[blockIdx.x * PTS_PER_BLOCK + t] = sqrtf(m);
  }
}

extern "C" void kernel_launch(void* const* d_in, const int* in_sizes, int n_in,
                              void* d_out, int out_size, void* d_ws, size_t ws_size,
                              hipStream_t stream) {
  const float* points = (const float*)d_in[0];     // (204800, 2)
  const float* gt_bboxes = (const float*)d_in[1];  // (256, 4)
  // d_in[2] strides: unused by the reference output.
  float* out = (float*)d_out;                      // (204800,)

  centerness_kernel<<<GRID, BLOCK, 0, stream>>>(points, gt_bboxes, out);
}